// Round 7
// baseline (279.683 us; speedup 1.0000x reference)
//
#include <hip/hip_runtime.h>
#include <hip/hip_bf16.h>
#include <math.h>

#define D 128
#define AGG_THREADS 128
#define CHUNK 512
#define BSHIFT 8                 // 256 dst nodes per bucket
#define MAXB 1024                // max buckets (LDS arrays)
#define MAXWG 1024               // max partition WGs (LDS arrays in bucket kernel)
#define PCHUNK 4096              // edges per partition WG
#define PE 16                    // PCHUNK / 256
#define EBUF_CAP 5120            // LDS staging cap in bucket kernel (mean 4096, 16 sigma)
#define PR 8192                  // perm region stride per bucket

// ---------- helpers ----------
__device__ __forceinline__ unsigned short f2bf(float f) {
    union { float f; unsigned int u; } c; c.f = f;
    unsigned int u = c.u;
    unsigned int r = (u + 0x7FFFu + ((u >> 16) & 1u)) >> 16;  // RNE
    return (unsigned short)r;
}
__device__ __forceinline__ void unpack2(unsigned int w, float& lo, float& hi) {
    union { unsigned int u; float f; } c;
    c.u = w << 16;          lo = c.f;
    c.u = w & 0xFFFF0000u;  hi = c.f;
}

// ---------- phase1: fused [partition blocks | prep blocks] ----------
// Blocks [0,nwg): WG-local counting sort of a 4096-edge chunk by dst-bucket,
// zero global atomics, packed 4B edges (src | ldst<<24).
// Blocks [nwg, ...): el/er dots + bf16 copy of feat_src (no LDS use).
__global__ __launch_bounds__(256) void phase1_kernel(
        const float* __restrict__ feat_src, const float* __restrict__ feat_dst,
        const float* __restrict__ attn_l,  const float* __restrict__ attn_r,
        float* __restrict__ el, float* __restrict__ er,
        unsigned short* __restrict__ feat_bf,
        const int* __restrict__ src, const int* __restrict__ dst,
        int E, int nbk, int nwg,
        unsigned* __restrict__ bins, int* __restrict__ cnt_tab, int* __restrict__ loc_tab,
        int Ns, int Nd) {
    __shared__ int hist[MAXB];
    __shared__ int lstart[MAXB];
    __shared__ int cursor[MAXB];
    __shared__ unsigned sbuf[PCHUNK];      // 16 KB
    int tid = threadIdx.x;

    if ((int)blockIdx.x < nwg) {
        // ---- partition block ----
        int w = blockIdx.x;
        int e0 = w * PCHUNK;
        int e1 = min(E, e0 + PCHUNK);
        int n = e1 - e0;

        for (int i = tid; i < nbk; i += 256) hist[i] = 0;
        __syncthreads();

        unsigned pv[PE]; int bk[PE];
        #pragma unroll
        for (int k = 0; k < PE; ++k) {
            int idx = e0 + k * 256 + tid;
            if (idx < e1) {
                int s = src[idx], j = dst[idx];
                bk[k] = j >> BSHIFT;
                pv[k] = (unsigned)s | ((unsigned)(j & 255) << 24);
                atomicAdd(&hist[bk[k]], 1);
            }
        }
        __syncthreads();

        if (tid < 64) {                    // wave-0 exclusive scan of hist
            int carry = 0;
            for (int c = 0; c < nbk; c += 64) {
                int i = c + tid;
                int v = (i < nbk) ? hist[i] : 0;
                int x = v;
                #pragma unroll
                for (int off = 1; off < 64; off <<= 1) {
                    int t = __shfl_up(x, off, 64);
                    if (tid >= off) x += t;
                }
                if (i < nbk) lstart[i] = x - v + carry;
                carry += __shfl(x, 63, 64);
            }
        }
        __syncthreads();

        for (int i = tid; i < nbk; i += 256) {
            cnt_tab[(size_t)w * nbk + i] = hist[i];
            loc_tab[(size_t)w * nbk + i] = lstart[i];
            cursor[i] = 0;
        }
        __syncthreads();

        #pragma unroll
        for (int k = 0; k < PE; ++k) {
            int idx = e0 + k * 256 + tid;
            if (idx < e1) {
                int b = bk[k];
                int r = lstart[b] + atomicAdd(&cursor[b], 1);
                sbuf[r] = pv[k];
            }
        }
        __syncthreads();

        unsigned* obase = bins + (size_t)w * PCHUNK;
        for (int t = tid; t < n; t += 256) obase[t] = sbuf[t];   // coalesced
    } else {
        // ---- prep block ----
        int blk = blockIdx.x - nwg;
        int half = tid >> 5, lane = tid & 31;
        int node = blk * 8 + half;
        if (node >= Ns + Nd) return;
        bool is_src = node < Ns;
        const float* feat = is_src ? feat_src + (size_t)node * D
                                   : feat_dst + (size_t)(node - Ns) * D;
        const float* attn = is_src ? attn_l : attn_r;
        float4 a = ((const float4*)attn)[lane];
        float4 v = ((const float4*)feat)[lane];
        if (is_src) {
            ushort4 h; h.x = f2bf(v.x); h.y = f2bf(v.y); h.z = f2bf(v.z); h.w = f2bf(v.w);
            ((ushort4*)(feat_bf + (size_t)node * D))[lane] = h;
        }
        float s = v.x * a.x + v.y * a.y + v.z * a.z + v.w * a.w;
        #pragma unroll
        for (int off = 16; off > 0; off >>= 1)
            s += __shfl_xor(s, off, 64);   // xor<=16 stays within 32-lane half
        if (lane == 0) {
            if (is_src) el[node] = s;
            else        er[node - Ns] = s;
        }
    }
}

// ---------- bucket: gather segments (coalesced) -> count -> scan -> rank -> perm ----------
__global__ __launch_bounds__(256) void bucket_kernel(
        const unsigned* __restrict__ bins,
        const int* __restrict__ cnt_tab, const int* __restrict__ loc_tab,
        int nbk, int nwg,
        int* __restrict__ counts, int* __restrict__ offs,
        int* __restrict__ perm, int Nd) {
    __shared__ unsigned ebuf[EBUF_CAP];    // 20 KB
    __shared__ int wcnt[MAXWG];
    __shared__ int wdst[MAXWG];
    __shared__ int wloc[MAXWG];
    __shared__ int cnt256[256];
    __shared__ int off256[256];
    __shared__ int cur256[256];
    __shared__ int tile[256];
    __shared__ int total_sh;

    int b = blockIdx.x, tid = threadIdx.x;
    int base = b << BSHIFT;

    for (int i = tid; i < nwg; i += 256) {
        wcnt[i] = cnt_tab[(size_t)i * nbk + b];
        wloc[i] = loc_tab[(size_t)i * nbk + b];
    }
    __syncthreads();
    if (tid < 64) {                        // exclusive scan over segment counts
        int carry = 0;
        for (int c = 0; c < nwg; c += 64) {
            int i = c + tid;
            int v = (i < nwg) ? wcnt[i] : 0;
            int x = v;
            #pragma unroll
            for (int off = 1; off < 64; off <<= 1) {
                int t = __shfl_up(x, off, 64);
                if (tid >= off) x += t;
            }
            if (i < nwg) wdst[i] = x - v + carry;
            carry += __shfl(x, 63, 64);
        }
        if (tid == 0) total_sh = carry;
    }
    cnt256[tid] = 0;
    cur256[tid] = 0;
    __syncthreads();
    int n = total_sh;
    bool fits = (n <= EBUF_CAP);

    if (fits) {
        // flat cooperative staging: thread t -> element t, segment via binary search
        for (int t = tid; t < n; t += 256) {
            int lo = 0, hi = nwg - 1;
            while (lo < hi) { int mid = (lo + hi + 1) >> 1; if (wdst[mid] <= t) lo = mid; else hi = mid - 1; }
            ebuf[t] = bins[(size_t)lo * PCHUNK + wloc[lo] + (t - wdst[lo])];
        }
        __syncthreads();
        for (int t = tid; t < n; t += 256)
            atomicAdd(&cnt256[ebuf[t] >> 24], 1);
    } else {
        // slow path (statistically unreachable)
        for (int w = tid; w < nwg; w += 256) {
            int c = wcnt[w];
            const unsigned* sp = bins + (size_t)w * PCHUNK + wloc[w];
            for (int k = 0; k < c; ++k)
                atomicAdd(&cnt256[sp[k] >> 24], 1);
        }
    }
    __syncthreads();

    // 256-wide exclusive scan of per-dst counts
    int v = cnt256[tid];
    tile[tid] = v;
    __syncthreads();
    for (int off = 1; off < 256; off <<= 1) {
        int t = (tid >= off) ? tile[tid - off] : 0;
        __syncthreads();
        tile[tid] += t;
        __syncthreads();
    }
    int myoff = tile[tid] - v;
    off256[tid] = myoff;
    int i = base + tid;
    if (i < Nd) {
        int c = v;
        if (myoff + c > PR) c = max(0, PR - myoff);   // paranoia clamp
        counts[i] = c;
        offs[i]   = myoff;
    }
    __syncthreads();

    size_t rbase = (size_t)b * PR;
    if (fits) {
        for (int t = tid; t < n; t += 256) {
            unsigned e = ebuf[t];
            int d = e >> 24;
            int r = atomicAdd(&cur256[d], 1);
            int slot = off256[d] + r;
            if (slot < PR) perm[rbase + slot] = (int)(e & 0xFFFFFFu);
        }
    } else {
        for (int w = tid; w < nwg; w += 256) {
            int c = wcnt[w];
            const unsigned* sp = bins + (size_t)w * PCHUNK + wloc[w];
            for (int k = 0; k < c; ++k) {
                unsigned e = sp[k];
                int d = e >> 24;
                int r = atomicAdd(&cur256[d], 1);
                int slot = off256[d] + r;
                if (slot < PR) perm[rbase + slot] = (int)(e & 0xFFFFFFu);
            }
        }
    }
}

// ---------- block reductions (128 threads = 2 waves) ----------
__device__ __forceinline__ float block_max128(float v, float* red, int tid) {
    #pragma unroll
    for (int off = 32; off > 0; off >>= 1)
        v = fmaxf(v, __shfl_down(v, off, 64));
    __syncthreads();
    if ((tid & 63) == 0) red[tid >> 6] = v;
    __syncthreads();
    return fmaxf(red[0], red[1]);
}
__device__ __forceinline__ float block_sum128(float v, float* red, int tid) {
    #pragma unroll
    for (int off = 32; off > 0; off >>= 1)
        v += __shfl_down(v, off, 64);
    __syncthreads();
    if ((tid & 63) == 0) red[tid >> 6] = v;
    __syncthreads();
    return red[0] + red[1];
}

// ---------- bf16-vectorized aggregate (bucket-region perm layout) ----------
__global__ void gat_aggregate_bf16_kernel(const unsigned short* __restrict__ feat_bf,
                                          const float* __restrict__ el,
                                          const float* __restrict__ er,
                                          const int* __restrict__ offs,
                                          const int* __restrict__ counts,
                                          const int* __restrict__ perm,
                                          float* __restrict__ out, int Nd) {
    __shared__ float w_sh[CHUNK];
    __shared__ int   s_sh[CHUNK];
    __shared__ float red[2];
    __shared__ float acc_sh[8][D];

    int j = blockIdx.x;
    int tid = threadIdx.x;
    int cnt = counts[j];
    size_t orow = (size_t)j * D;
    if (cnt == 0) { out[orow + tid] = 0.0f; return; }

    size_t beg = (size_t)(j >> BSHIFT) * PR + offs[j];
    float erj = er[j];
    int g = tid >> 4, u = tid & 15;
    float acc[8];
    #pragma unroll
    for (int k = 0; k < 8; ++k) acc[k] = 0.0f;
    float inv;
    const unsigned short* fb = feat_bf + (size_t)u * 8;

    if (cnt <= CHUNK) {
        float lmax = -INFINITY;
        for (int t = tid; t < cnt; t += AGG_THREADS) {
            int s = perm[beg + t];
            float e = el[s] + erj;
            e = (e >= 0.0f) ? e : 0.01f * e;  // leaky_relu
            s_sh[t] = s;
            w_sh[t] = e;
            lmax = fmaxf(lmax, e);
        }
        float m = block_max128(lmax, red, tid);
        float lsum = 0.0f;
        for (int t = tid; t < cnt; t += AGG_THREADS) {
            float a = __expf(w_sh[t] - m);
            w_sh[t] = a;
            lsum += a;
        }
        float den = block_sum128(lsum, red, tid);
        inv = 1.0f / den;
        __syncthreads();
        for (int t = g; t < cnt; t += 8) {
            int s = s_sh[t];
            float w = w_sh[t];
            uint4 v = *(const uint4*)(fb + (size_t)s * D);
            float f[8];
            unpack2(v.x, f[0], f[1]); unpack2(v.y, f[2], f[3]);
            unpack2(v.z, f[4], f[5]); unpack2(v.w, f[6], f[7]);
            #pragma unroll
            for (int k = 0; k < 8; ++k) acc[k] += w * f[k];
        }
    } else {
        float lmax = -INFINITY;
        for (int t = tid; t < cnt; t += AGG_THREADS) {
            int s = perm[beg + t];
            float e = el[s] + erj;
            e = (e >= 0.0f) ? e : 0.01f * e;
            lmax = fmaxf(lmax, e);
        }
        float m = block_max128(lmax, red, tid);
        float lsum = 0.0f;
        for (int t = tid; t < cnt; t += AGG_THREADS) {
            int s = perm[beg + t];
            float e = el[s] + erj;
            e = (e >= 0.0f) ? e : 0.01f * e;
            lsum += __expf(e - m);
        }
        float den = block_sum128(lsum, red, tid);
        inv = 1.0f / den;
        for (int bb = 0; bb < cnt; bb += CHUNK) {
            int n = min(CHUNK, cnt - bb);
            __syncthreads();
            for (int t = tid; t < n; t += AGG_THREADS) {
                int s = perm[beg + bb + t];
                float e = el[s] + erj;
                e = (e >= 0.0f) ? e : 0.01f * e;
                s_sh[t] = s;
                w_sh[t] = __expf(e - m);
            }
            __syncthreads();
            for (int t = g; t < n; t += 8) {
                int s = s_sh[t];
                float w = w_sh[t];
                uint4 v = *(const uint4*)(fb + (size_t)s * D);
                float f[8];
                unpack2(v.x, f[0], f[1]); unpack2(v.y, f[2], f[3]);
                unpack2(v.z, f[4], f[5]); unpack2(v.w, f[6], f[7]);
                #pragma unroll
                for (int k = 0; k < 8; ++k) acc[k] += w * f[k];
            }
        }
    }
    #pragma unroll
    for (int k = 0; k < 8; ++k) acc_sh[g][u * 8 + k] = acc[k];
    __syncthreads();
    float r = 0.0f;
    #pragma unroll
    for (int g2 = 0; g2 < 8; ++g2) r += acc_sh[g2][tid];
    out[orow + tid] = r * inv;
}

// ================= fallback pipeline (workspace too small / shape out of range) =================
__global__ void prep_fb_kernel(const float* __restrict__ feat_src,
                               const float* __restrict__ feat_dst,
                               const float* __restrict__ attn_l,
                               const float* __restrict__ attn_r,
                               float* __restrict__ el, float* __restrict__ er,
                               int Ns, int Nd) {
    int half = threadIdx.x >> 5, lane = threadIdx.x & 31;
    int node = blockIdx.x * 8 + half;
    if (node >= Ns + Nd) return;
    bool is_src = node < Ns;
    const float* feat = is_src ? feat_src + (size_t)node * D
                               : feat_dst + (size_t)(node - Ns) * D;
    const float* attn = is_src ? attn_l : attn_r;
    float4 a = ((const float4*)attn)[lane];
    float4 v = ((const float4*)feat)[lane];
    float s = v.x * a.x + v.y * a.y + v.z * a.z + v.w * a.w;
    #pragma unroll
    for (int off = 16; off > 0; off >>= 1)
        s += __shfl_xor(s, off, 64);
    if (lane == 0) {
        if (is_src) el[node] = s;
        else        er[node - Ns] = s;
    }
}
__global__ void hist_kernel(const int* __restrict__ dst, int E, int* __restrict__ counts) {
    int stride = gridDim.x * blockDim.x;
    for (int k = blockIdx.x * blockDim.x + threadIdx.x; k < E; k += stride)
        atomicAdd(&counts[dst[k]], 1);
}
__global__ void scan1_kernel(const int* __restrict__ counts, int* __restrict__ offsets,
                             int* __restrict__ blockSums, int N) {
    __shared__ int tile[256];
    int tid = threadIdx.x;
    int i = blockIdx.x * 256 + tid;
    int v = (i < N) ? counts[i] : 0;
    tile[tid] = v;
    __syncthreads();
    for (int off = 1; off < 256; off <<= 1) {
        int t = (tid >= off) ? tile[tid - off] : 0;
        __syncthreads();
        tile[tid] += t;
        __syncthreads();
    }
    int incl = tile[tid];
    if (i < N) offsets[i] = incl - v;
    if (tid == 255) blockSums[blockIdx.x] = incl;
}
__global__ void scan2_kernel(int* __restrict__ bs, int nb) {
    __shared__ int tile[256];
    int tid = threadIdx.x;
    int carry = 0;
    for (int base = 0; base < nb; base += 256) {
        int i = base + tid;
        int v = (i < nb) ? bs[i] : 0;
        __syncthreads();
        tile[tid] = v;
        __syncthreads();
        for (int off = 1; off < 256; off <<= 1) {
            int t = (tid >= off) ? tile[tid - off] : 0;
            __syncthreads();
            tile[tid] += t;
            __syncthreads();
        }
        int incl = tile[tid];
        if (i < nb) bs[i] = incl - v + carry;
        carry += tile[255];
    }
}
__global__ void fill_kernel(const int* __restrict__ src, const int* __restrict__ dst, int E,
                            const int* __restrict__ offsets, const int* __restrict__ bsum,
                            int* __restrict__ cursor, int* __restrict__ perm_src) {
    int stride = gridDim.x * blockDim.x;
    for (int k = blockIdx.x * blockDim.x + threadIdx.x; k < E; k += stride) {
        int j = dst[k];
        int p = offsets[j] + bsum[j >> BSHIFT] + atomicAdd(&cursor[j], 1);
        perm_src[p] = src[k];
    }
}
__global__ void gat_aggregate_f32_kernel(const float* __restrict__ feat_src,
                                         const float* __restrict__ el,
                                         const float* __restrict__ er,
                                         const int* __restrict__ offsets,
                                         const int* __restrict__ bsum,
                                         const int* __restrict__ counts,
                                         const int* __restrict__ perm_src,
                                         float* __restrict__ out, int Nd) {
    __shared__ float w_sh[CHUNK];
    __shared__ int   s_sh[CHUNK];
    __shared__ float red[2];
    int j = blockIdx.x;
    int tid = threadIdx.x;
    int cnt = counts[j];
    size_t orow = (size_t)j * D;
    if (cnt == 0) { out[orow + tid] = 0.0f; return; }
    int beg = offsets[j] + bsum[j >> BSHIFT];
    float erj = er[j];
    float acc = 0.0f;
    float inv;
    if (cnt <= CHUNK) {
        float lmax = -INFINITY;
        for (int t = tid; t < cnt; t += AGG_THREADS) {
            int s = perm_src[beg + t];
            float e = el[s] + erj;
            e = (e >= 0.0f) ? e : 0.01f * e;
            s_sh[t] = s; w_sh[t] = e;
            lmax = fmaxf(lmax, e);
        }
        float m = block_max128(lmax, red, tid);
        float lsum = 0.0f;
        for (int t = tid; t < cnt; t += AGG_THREADS) {
            float a = __expf(w_sh[t] - m);
            w_sh[t] = a; lsum += a;
        }
        float den = block_sum128(lsum, red, tid);
        inv = 1.0f / den;
        __syncthreads();
        for (int t = 0; t < cnt; ++t)
            acc += feat_src[(size_t)s_sh[t] * D + tid] * w_sh[t];
    } else {
        float lmax = -INFINITY;
        for (int t = tid; t < cnt; t += AGG_THREADS) {
            int s = perm_src[beg + t];
            float e = el[s] + erj;
            e = (e >= 0.0f) ? e : 0.01f * e;
            lmax = fmaxf(lmax, e);
        }
        float m = block_max128(lmax, red, tid);
        float lsum = 0.0f;
        for (int t = tid; t < cnt; t += AGG_THREADS) {
            int s = perm_src[beg + t];
            float e = el[s] + erj;
            e = (e >= 0.0f) ? e : 0.01f * e;
            lsum += __expf(e - m);
        }
        float den = block_sum128(lsum, red, tid);
        inv = 1.0f / den;
        for (int bb = 0; bb < cnt; bb += CHUNK) {
            int n = min(CHUNK, cnt - bb);
            __syncthreads();
            for (int t = tid; t < n; t += AGG_THREADS) {
                int s = perm_src[beg + bb + t];
                float e = el[s] + erj;
                e = (e >= 0.0f) ? e : 0.01f * e;
                s_sh[t] = s;
                w_sh[t] = __expf(e - m);
            }
            __syncthreads();
            for (int t = 0; t < n; ++t)
                acc += feat_src[(size_t)s_sh[t] * D + tid] * w_sh[t];
        }
    }
    out[orow + tid] = acc * inv;
}

extern "C" void kernel_launch(void* const* d_in, const int* in_sizes, int n_in,
                              void* d_out, int out_size, void* d_ws, size_t ws_size,
                              hipStream_t stream) {
    const float* feat_src = (const float*)d_in[0];
    const float* feat_dst = (const float*)d_in[1];
    const int*   src      = (const int*)d_in[2];
    const int*   dst      = (const int*)d_in[3];
    const float* attn_l   = (const float*)d_in[4];
    const float* attn_r   = (const float*)d_in[5];
    float* out = (float*)d_out;

    int Ns = in_sizes[0] / D;
    int Nd = in_sizes[1] / D;
    int E  = in_sizes[2];
    int NBK = (Nd + (1 << BSHIFT) - 1) >> BSHIFT;
    int NWG = (E + PCHUNK - 1) / PCHUNK;

    char* p = (char*)d_ws;
    auto carve = [&](size_t bytes) { void* r = (void*)p; p += (bytes + 255) & ~(size_t)255; return r; };
    float*    el      = (float*)carve((size_t)Ns * 4);
    float*    er      = (float*)carve((size_t)Nd * 4);
    int*      counts  = (int*)carve((size_t)Nd * 4);
    int*      offs    = (int*)carve((size_t)Nd * 4);
    int*      gcursor = (int*)carve((size_t)Nd * 4);       // fallback only
    int*      bsums   = (int*)carve((size_t)NBK * 4);      // fallback only
    int*      cnt_tab = (int*)carve((size_t)NWG * NBK * 4);
    int*      loc_tab = (int*)carve((size_t)NWG * NBK * 4);
    int*      perm    = (int*)carve((size_t)NBK * PR * 4); // >= E*4, shared w/ fallback
    unsigned* bins    = (unsigned*)carve((size_t)NWG * PCHUNK * 4);
    size_t used       = (size_t)(p - (char*)d_ws);
    size_t bf_bytes   = (size_t)Ns * D * 2;
    unsigned short* feat_bf = (unsigned short*)carve(bf_bytes);

    int fast = (NBK <= MAXB && NWG <= MAXWG && Ns <= (1 << 24) &&
                used + bf_bytes + 256 <= ws_size) ? 1 : 0;

    int total = Ns + Nd;
    int prep_blocks = (total + 7) / 8;
    if (fast) {
        phase1_kernel<<<NWG + prep_blocks, 256, 0, stream>>>(
            feat_src, feat_dst, attn_l, attn_r, el, er, feat_bf,
            src, dst, E, NBK, NWG, bins, cnt_tab, loc_tab, Ns, Nd);
        bucket_kernel<<<NBK, 256, 0, stream>>>(bins, cnt_tab, loc_tab, NBK, NWG,
                                               counts, offs, perm, Nd);
        gat_aggregate_bf16_kernel<<<Nd, AGG_THREADS, 0, stream>>>(feat_bf, el, er, offs,
                                                                  counts, perm, out, Nd);
    } else {
        hipMemsetAsync(counts, 0, (size_t)Nd * 4, stream);
        hipMemsetAsync(gcursor, 0, (size_t)Nd * 4, stream);
        prep_fb_kernel<<<prep_blocks, 256, 0, stream>>>(feat_src, feat_dst, attn_l, attn_r,
                                                        el, er, Ns, Nd);
        hist_kernel<<<2048, 256, 0, stream>>>(dst, E, counts);
        scan1_kernel<<<NBK, 256, 0, stream>>>(counts, offs, bsums, Nd);
        scan2_kernel<<<1, 256, 0, stream>>>(bsums, NBK);
        fill_kernel<<<2048, 256, 0, stream>>>(src, dst, E, offs, bsums, gcursor, perm);
        gat_aggregate_f32_kernel<<<Nd, AGG_THREADS, 0, stream>>>(feat_src, el, er, offs,
                                                                 bsums, counts, perm, out, Nd);
    }
}